// Round 2
// baseline (3314.909 us; speedup 1.0000x reference)
//
#include <hip/hip_runtime.h>
#include <math.h>

#define NT 12000
#define NO 24000
#define RANKC 32
#define KORD 10
#define E0C 384000
#define E1C 384000
#define E2C 192000

static __device__ __forceinline__ float waveSum(float v) {
  v += __shfl_xor(v, 32, 64);
  v += __shfl_xor(v, 16, 64);
  v += __shfl_xor(v, 8, 64);
  v += __shfl_xor(v, 4, 64);
  v += __shfl_xor(v, 2, 64);
  v += __shfl_xor(v, 1, 64);
  return v;
}

__global__ void k_deg(const int* __restrict__ idx, float* __restrict__ deg, int E) {
  int i = blockIdx.x * blockDim.x + threadIdx.x;
  if (i < E) atomicAdd(&deg[idx[i]], 1.0f);
}

__global__ void k_histi(const int* __restrict__ idx, int* __restrict__ cnt, int E) {
  int i = blockIdx.x * blockDim.x + threadIdx.x;
  if (i < E) atomicAdd(&cnt[idx[i]], 1);
}

__global__ void k_rs(float* __restrict__ d, int n) {
  int i = blockIdx.x * blockDim.x + threadIdx.x;
  if (i < n) d[i] = 1.0f / sqrtf(fmaxf(d[i], 1.0f));
}

// single-block exclusive scan of cnt[0..n) -> rowptr[0..n]
__global__ void k_scan(const int* __restrict__ cnt, int* __restrict__ rowptr, int n) {
  __shared__ int wsum[4];
  __shared__ int carry;
  int tid = threadIdx.x, lane = tid & 63, wid = tid >> 6;
  if (tid == 0) carry = 0;
  __syncthreads();
  for (int base = 0; base < n; base += 256) {
    int i = base + tid;
    int v = (i < n) ? cnt[i] : 0;
    int s = v;
#pragma unroll
    for (int d = 1; d < 64; d <<= 1) {
      int t = __shfl_up(s, d, 64);
      if (lane >= d) s += t;
    }
    if (lane == 63) wsum[wid] = s;
    __syncthreads();
    int woff = carry;
    for (int w = 0; w < wid; ++w) woff += wsum[w];
    if (i < n) rowptr[i] = woff + s - v;
    __syncthreads();
    if (tid == 0) carry += wsum[0] + wsum[1] + wsum[2] + wsum[3];
    __syncthreads();
  }
  if (threadIdx.x == 0) rowptr[n] = carry;
}

__global__ void k_fill(const int* __restrict__ src, const int* __restrict__ dst,
                       const int* __restrict__ rowptr, int* __restrict__ fill,
                       int* __restrict__ eidx, int E) {
  int e = blockIdx.x * blockDim.x + threadIdx.x;
  if (e >= E) return;
  int d = dst[e];
  int pos = rowptr[d] + atomicAdd(&fill[d], 1);
  eidx[pos] = src[e];
}

// out[n][c] = sum_k X[n][k]*W[k][c] + b[c]; 4 rows/block, 64 cols
template<int K>
__global__ void k_gemmN64(const float* __restrict__ X, const float* __restrict__ W,
                          const float* __restrict__ b, float* __restrict__ out, int N) {
  int row = blockIdx.x * 4 + (threadIdx.x >> 6);
  int c = threadIdx.x & 63;
  if (row >= N) return;
  const float* x = X + (size_t)row * K;
  float acc = b[c];
#pragma unroll 2
  for (int k = 0; k < K; ++k) acc = fmaf(x[k], W[k * 64 + c], acc);
  out[(size_t)row * 64 + c] = acc;
}

// Fused CSR-gather + deg-norm + (agg@W + b) + optional attention-score partial.
// One wave per dst row, 4 rows/block. No atomics on the feature matrix.
template<int ATT>
__global__ void k_rowagg(const float* __restrict__ X, const float* __restrict__ rss,
                         const float* __restrict__ rsd,
                         const int* __restrict__ rowptr, const int* __restrict__ eidx,
                         const float* __restrict__ W, const float* __restrict__ b,
                         const float* __restrict__ fcW, const float* __restrict__ fcb,
                         const float* __restrict__ v, float* __restrict__ score,
                         float* __restrict__ out, int N) {
  __shared__ float sm[4][64];
  int wid = threadIdx.x >> 6, lane = threadIdx.x & 63;
  int row = blockIdx.x * 4 + wid;
  if (row >= N) return;  // grids are exact (N % 4 == 0), never taken
  int p0 = rowptr[row], p1 = rowptr[row + 1];
  float acc = 0.f;
  int p = p0;
  for (; p + 3 < p1; p += 4) {
    int s0 = eidx[p], s1 = eidx[p + 1], s2 = eidx[p + 2], s3 = eidx[p + 3];
    float r0 = rss[s0], r1 = rss[s1], r2 = rss[s2], r3 = rss[s3];
    acc = fmaf(X[(size_t)s0 * 64 + lane], r0, acc);
    acc = fmaf(X[(size_t)s1 * 64 + lane], r1, acc);
    acc = fmaf(X[(size_t)s2 * 64 + lane], r2, acc);
    acc = fmaf(X[(size_t)s3 * 64 + lane], r3, acc);
  }
  for (; p < p1; ++p) {
    int s = eidx[p];
    acc = fmaf(X[(size_t)s * 64 + lane], rss[s], acc);
  }
  acc *= rsd[row];
  sm[wid][lane] = acc;
  __syncthreads();
  float m = b[lane];
#pragma unroll
  for (int k = 0; k < 64; ++k) m = fmaf(sm[wid][k], W[k * 64 + lane], m);
  out[(size_t)row * 64 + lane] = m;
  if (ATT) {
    __syncthreads();
    sm[wid][lane] = m;
    __syncthreads();
    float fa = fcb[lane];
#pragma unroll
    for (int k = 0; k < 64; ++k) fa = fmaf(sm[wid][k], fcW[k * 64 + lane], fa);
    float part = tanhf(fa) * v[lane];
    part = waveSum(part);
    if (lane == 0) atomicAdd(score, part);
  }
}

// hidden init: eta from Tx via proj head kidx, hidden = Tx*eta
__global__ void k_gpr(const float* __restrict__ Tx, const float* __restrict__ projW,
                      const float* __restrict__ projb, const float* __restrict__ gamma,
                      int kidx, float* __restrict__ hidden, int N) {
  int row = blockIdx.x * 4 + (threadIdx.x >> 6);
  int lane = threadIdx.x & 63;
  if (row >= N) return;
  const float* tx = Tx + (size_t)row * 64;
  float part = 0.f;
  if (lane < 32) {
    const float* pw = projW + (size_t)kidx * (64 * 32);
    float acc = projb[kidx * 32 + lane];
#pragma unroll
    for (int k = 0; k < 64; ++k) acc = fmaf(tx[k], pw[k * 32 + lane], acc);
    part = tanhf(acc) * gamma[lane * (KORD + 1) + kidx];
  }
  part = waveSum(part);
  float eta = part * (1.0f / RANKC);
  hidden[(size_t)row * 64 + lane] = tx[lane] * eta;
}

// Fused: softmax-combine (+Chebyshev) -> Tx2out, then GPR head accumulate into hidden.
__global__ void k_combgpr(const float* __restrict__ m0, const float* __restrict__ m1,
                          const float* __restrict__ sc, int slot0, int slot1, float invN,
                          const float* __restrict__ Tx0, float* __restrict__ Tx2out,
                          const float* __restrict__ projW, const float* __restrict__ projb,
                          const float* __restrict__ gamma, int kidx,
                          float* __restrict__ hidden, int N, int cheb) {
  __shared__ float sm[4][64];
  int wid = threadIdx.x >> 6, lane = threadIdx.x & 63;
  int row = blockIdx.x * 4 + wid;
  if (row >= N) return;  // exact grid
  size_t o = (size_t)row * 64 + lane;
  float s0 = sc[slot0] * invN, s1 = sc[slot1] * invN;
  float mx = fmaxf(s0, s1);
  float e0 = expf(s0 - mx), e1 = expf(s1 - mx);
  float inv = 1.0f / (e0 + e1);
  float z = e0 * inv * m0[o] + e1 * inv * m1[o];
  float tx2 = cheb ? (2.0f * z - Tx0[o]) : z;
  Tx2out[o] = tx2;
  sm[wid][lane] = tx2;
  __syncthreads();
  float part = 0.f;
  if (lane < 32) {
    const float* pw = projW + (size_t)kidx * (64 * 32);
    float pa = projb[kidx * 32 + lane];
#pragma unroll
    for (int k = 0; k < 64; ++k) pa = fmaf(sm[wid][k], pw[k * 32 + lane], pa);
    part = tanhf(pa) * gamma[lane * (KORD + 1) + kidx];
  }
  part = waveSum(part);
  float eta = part * (1.0f / RANKC);
  hidden[o] += tx2 * eta;
}

// C = H @ H^T (symmetric). 128x128 tile per block, 8x8 per thread, k-major LDS,
// two 32-wide k phases (LDS 34 KB). Only bi<=bj computed; transpose written too.
__global__ __launch_bounds__(256) void k_adj(const float* __restrict__ H,
                                             float* __restrict__ C, int N) {
  int bi = blockIdx.x, bj = blockIdx.y;
  if (bi > bj) return;
  __shared__ float As[32][132];
  __shared__ float Bs[32][132];
  int tid = threadIdx.x;
  int tx = tid & 15, ty = tid >> 4;
  float acc[8][8] = {};
  for (int kt = 0; kt < 64; kt += 32) {
    {
      int c2 = tid & 7, rb = tid >> 3;  // c2: float4 col, rb: row 0..31
      int kk = c2 * 4;
#pragma unroll
      for (int l = 0; l < 4; ++l) {
        int r = l * 32 + rb;
        int gi = bi * 128 + r;
        float4 a = (gi < N) ? *reinterpret_cast<const float4*>(&H[(size_t)gi * 64 + kt + kk])
                            : make_float4(0.f, 0.f, 0.f, 0.f);
        As[kk + 0][r] = a.x; As[kk + 1][r] = a.y; As[kk + 2][r] = a.z; As[kk + 3][r] = a.w;
        int gj = bj * 128 + r;
        float4 bb = (gj < N) ? *reinterpret_cast<const float4*>(&H[(size_t)gj * 64 + kt + kk])
                             : make_float4(0.f, 0.f, 0.f, 0.f);
        Bs[kk + 0][r] = bb.x; Bs[kk + 1][r] = bb.y; Bs[kk + 2][r] = bb.z; Bs[kk + 3][r] = bb.w;
      }
    }
    __syncthreads();
#pragma unroll 8
    for (int k = 0; k < 32; ++k) {
      float4 a0 = *reinterpret_cast<const float4*>(&As[k][ty * 4]);
      float4 a1 = *reinterpret_cast<const float4*>(&As[k][64 + ty * 4]);
      float4 b0 = *reinterpret_cast<const float4*>(&Bs[k][tx * 4]);
      float4 b1 = *reinterpret_cast<const float4*>(&Bs[k][64 + tx * 4]);
      float av[8] = {a0.x, a0.y, a0.z, a0.w, a1.x, a1.y, a1.z, a1.w};
      float bv[8] = {b0.x, b0.y, b0.z, b0.w, b1.x, b1.y, b1.z, b1.w};
#pragma unroll
      for (int i = 0; i < 8; ++i)
#pragma unroll
        for (int j = 0; j < 8; ++j) acc[i][j] = fmaf(av[i], bv[j], acc[i][j]);
    }
    __syncthreads();
  }
  // normal store: rows {bi*128 + g*64 + ty*4 + i}, cols {bj*128 + h*64 + tx*4 ..+3}
#pragma unroll
  for (int g = 0; g < 2; ++g) {
#pragma unroll
    for (int i = 0; i < 4; ++i) {
      int gr = bi * 128 + g * 64 + ty * 4 + i;
      if (gr >= N) continue;
#pragma unroll
      for (int h = 0; h < 2; ++h) {
        int gc = bj * 128 + h * 64 + tx * 4;
        if (gc >= N) continue;
        float4 vv = make_float4(acc[g * 4 + i][h * 4 + 0], acc[g * 4 + i][h * 4 + 1],
                                acc[g * 4 + i][h * 4 + 2], acc[g * 4 + i][h * 4 + 3]);
        *reinterpret_cast<float4*>(&C[(size_t)gr * N + gc]) = vv;
      }
    }
  }
  if (bi != bj) {  // transpose tile; bi<bj => all source rows valid
#pragma unroll
    for (int h = 0; h < 2; ++h) {
#pragma unroll
      for (int j = 0; j < 4; ++j) {
        int gc = bj * 128 + h * 64 + tx * 4 + j;
        if (gc >= N) continue;
#pragma unroll
        for (int g = 0; g < 2; ++g) {
          int gr0 = bi * 128 + g * 64 + ty * 4;
          float4 tv = make_float4(acc[g * 4 + 0][h * 4 + j], acc[g * 4 + 1][h * 4 + j],
                                  acc[g * 4 + 2][h * 4 + j], acc[g * 4 + 3][h * 4 + j]);
          *reinterpret_cast<float4*>(&C[(size_t)gc * N + gr0]) = tv;
        }
      }
    }
  }
}

template<int K>
__global__ void k_rowgemm(const float* __restrict__ X, const float* __restrict__ W,
                          const float* __restrict__ b, float* __restrict__ out,
                          int NCOL, int act) {
  __shared__ float xs[K];
  int row = blockIdx.x;
  for (int k = threadIdx.x; k < K; k += blockDim.x) xs[k] = X[(size_t)row * K + k];
  __syncthreads();
  for (int c = threadIdx.x; c < NCOL; c += blockDim.x) {
    float acc = b[c];
#pragma unroll 4
    for (int k = 0; k < K; ++k) acc = fmaf(xs[k], W[k * NCOL + c], acc);
    if (act == 1) acc = fmaxf(acc, 0.f);
    else if (act == 2) acc = tanhf(acc);
    out[(size_t)row * NCOL + c] = acc;
  }
}

__global__ void k_tanhv(const float* __restrict__ in, float* __restrict__ out, int n) {
  int i = blockIdx.x * blockDim.x + threadIdx.x;
  if (i < n) out[i] = tanhf(in[i]);
}

__global__ void k_loss(const float* __restrict__ h, const float* __restrict__ zp,
                       float* __restrict__ accum, int N) {
  int row = blockIdx.x * 4 + (threadIdx.x >> 6);
  int lane = threadIdx.x & 63;
  if (row >= N) return;
  float hv = h[(size_t)row * 64 + lane];
  float zv = zp[(size_t)row * 64 + lane];
  float hm = waveSum(hv) * (1.0f / 64.0f);
  float zm = waveSum(zv) * (1.0f / 64.0f);
  float c = waveSum((hv - hm) * (zv - zm)) * (1.0f / 64.0f);
  if (lane == 0) atomicAdd(accum, c);
}

__global__ void k_finalize(const float* __restrict__ accum, float* __restrict__ out) {
  float s = accum[0] * (1.0f / NT);
  out[0] = s * s;  // loss_dis1 (1-row HSIC) is exactly 0
}

__global__ void k_logits(const float* __restrict__ h, const float* __restrict__ W,
                         const float* __restrict__ b, float* __restrict__ out, int N) {
  int i = blockIdx.x * blockDim.x + threadIdx.x;
  if (i >= N * 3) return;
  int n = i / 3, j = i % 3;
  const float* hr = h + (size_t)n * 64;
  float acc = b[j];
#pragma unroll
  for (int c = 0; c < 64; ++c) acc = fmaf(hr[c], W[c * 3 + j], acc);
  out[i] = acc;
}

extern "C" void kernel_launch(void* const* d_in, const int* in_sizes, int n_in,
                              void* d_out, int out_size, void* d_ws, size_t ws_size,
                              hipStream_t stream) {
  const float* features_v1 = (const float*)d_in[0];
  const float* feat_other  = (const float*)d_in[1];
  const float* z_pre = (const float*)d_in[2];
  const float* Wt = (const float*)d_in[3];   const float* bt = (const float*)d_in[4];
  const float* Wo = (const float*)d_in[5];   const float* bo = (const float*)d_in[6];
  const float* W1r0 = (const float*)d_in[7];  const float* b1r0 = (const float*)d_in[8];
  const float* W1r1 = (const float*)d_in[9];  const float* b1r1 = (const float*)d_in[10];
  const float* W1r2 = (const float*)d_in[11]; const float* b1r2 = (const float*)d_in[12];
  const float* att1_fcW = (const float*)d_in[13]; const float* att1_fcb = (const float*)d_in[14];
  const float* att1_v = (const float*)d_in[15];
  const float* W2r0 = (const float*)d_in[16]; const float* b2r0 = (const float*)d_in[17];
  // d_in[18]/d_in[19] (W2r1/b2r1) feed only the discarded loop out_o — unused.
  const float* W2r2 = (const float*)d_in[20]; const float* b2r2 = (const float*)d_in[21];
  const float* att2_fcW = (const float*)d_in[22]; const float* att2_fcb = (const float*)d_in[23];
  const float* att2_v = (const float*)d_in[24];
  const float* projW = (const float*)d_in[25]; const float* projb = (const float*)d_in[26];
  const float* gamma = (const float*)d_in[27];
  const float* p3W = (const float*)d_in[28]; const float* p3b = (const float*)d_in[29];
  const float* p1W1 = (const float*)d_in[30]; const float* p1b1 = (const float*)d_in[31];
  const float* p1W2 = (const float*)d_in[32]; const float* p1b2 = (const float*)d_in[33];
  const float* outW = (const float*)d_in[34]; const float* outb = (const float*)d_in[35];
  const int* src_r0 = (const int*)d_in[36]; const int* dst_r0 = (const int*)d_in[37];
  const int* src_r1 = (const int*)d_in[38]; const int* dst_r1 = (const int*)d_in[39];
  const int* src_r2 = (const int*)d_in[40]; const int* dst_r2 = (const int*)d_in[41];

  float* out = (float*)d_out;
  const size_t LOGITS_OFF = 0;
  const size_t H_OFF = (size_t)NT * 3;
  const size_t XPRE_OFF = H_OFF + (size_t)NT * 64;
  const size_t ZPRE_OFF = XPRE_OFF + (size_t)NT * 334;
  const size_t ADJ_OFF = ZPRE_OFF + (size_t)NT * 334;
  const size_t LOSS_OFF = ADJ_OFF + (size_t)NT * NT;

  float* ws = (float*)d_ws;
  size_t o = 0;
  auto alloc = [&](size_t n) { float* p = ws + o; o += n; return p; };
  float* Tx0_t = alloc((size_t)NT * 64);
  float* Tx1_t = alloc((size_t)NT * 64);
  float* Tx2_t = alloc((size_t)NT * 64);
  float* Tx0_o = alloc((size_t)NO * 64);
  float* Tx1_o = alloc((size_t)NO * 64);
  float* mt0   = alloc((size_t)NT * 64);
  float* mt2   = alloc((size_t)NT * 64);
  float* hidden = alloc((size_t)NT * 64);
  float* zp    = alloc((size_t)NT * 64);
  float* t1    = alloc((size_t)NT * 128);
  float* rs_s0 = alloc(NO);   // 6 degree arrays contiguous: 96000 floats
  float* rs_d0 = alloc(NT);
  float* rs_s1 = alloc(NT);
  float* rs_d1 = alloc(NO);
  float* rs_s2 = alloc(NT);
  float* rs_d2 = alloc(NT);
  float* sc = alloc(16);      // slots 0..11 att scores, 12 loss accum (zeroed with rs block)

  int* ip = (int*)(ws + o);
  auto ialloc = [&](size_t n) { int* p = ip; ip += n; return p; };
  int* cnt0 = ialloc(NT);  int* cnt1 = ialloc(NO);  int* cnt2 = ialloc(NT);
  int* fil0 = ialloc(NT);  int* fil1 = ialloc(NO);  int* fil2 = ialloc(NT);
  int* rp0 = ialloc(NT + 1); int* rp1 = ialloc(NO + 1); int* rp2 = ialloc(NT + 1);
  int* ei0 = ialloc(E0C); int* ei1 = ialloc(E1C); int* ei2 = ialloc(E2C);

  const int BT = 256;
  const int gNT = NT / 4;   // 3000
  const int gNO = NO / 4;   // 6000

  // ---- zero accumulators (must happen every call) ----
  hipMemsetAsync(rs_s0, 0, (96000 + 16) * sizeof(float), stream);      // deg + sc
  hipMemsetAsync(cnt0, 0, (size_t)(2 * (NT + NO + NT)) * sizeof(int), stream);  // cnt + fill

  // ---- degrees ----
  k_deg<<<(E0C + BT - 1) / BT, BT, 0, stream>>>(src_r0, rs_s0, E0C);
  k_deg<<<(E0C + BT - 1) / BT, BT, 0, stream>>>(dst_r0, rs_d0, E0C);
  k_deg<<<(E1C + BT - 1) / BT, BT, 0, stream>>>(src_r1, rs_s1, E1C);
  k_deg<<<(E1C + BT - 1) / BT, BT, 0, stream>>>(dst_r1, rs_d1, E1C);
  k_deg<<<(E2C + BT - 1) / BT, BT, 0, stream>>>(src_r2, rs_s2, E2C);
  k_deg<<<(E2C + BT - 1) / BT, BT, 0, stream>>>(dst_r2, rs_d2, E2C);
  k_rs<<<96000 / BT, BT, 0, stream>>>(rs_s0, 96000);

  // ---- CSR build (by dst) ----
  k_histi<<<(E0C + BT - 1) / BT, BT, 0, stream>>>(dst_r0, cnt0, E0C);
  k_histi<<<(E1C + BT - 1) / BT, BT, 0, stream>>>(dst_r1, cnt1, E1C);
  k_histi<<<(E2C + BT - 1) / BT, BT, 0, stream>>>(dst_r2, cnt2, E2C);
  k_scan<<<1, 256, 0, stream>>>(cnt0, rp0, NT);
  k_scan<<<1, 256, 0, stream>>>(cnt1, rp1, NO);
  k_scan<<<1, 256, 0, stream>>>(cnt2, rp2, NT);
  k_fill<<<(E0C + BT - 1) / BT, BT, 0, stream>>>(src_r0, dst_r0, rp0, fil0, ei0, E0C);
  k_fill<<<(E1C + BT - 1) / BT, BT, 0, stream>>>(src_r1, dst_r1, rp1, fil1, ei1, E1C);
  k_fill<<<(E2C + BT - 1) / BT, BT, 0, stream>>>(src_r2, dst_r2, rp2, fil2, ei2, E2C);

  // ---- input projections ----
  k_gemmN64<334><<<gNT, BT, 0, stream>>>(features_v1, Wt, bt, Tx0_t, NT);
  k_gemmN64<128><<<gNO, BT, 0, stream>>>(feat_other, Wo, bo, Tx0_o, NO);

  // ---- layer 1 hconv (gather, no atomics) ----
  k_rowagg<1><<<gNT, BT, 0, stream>>>(Tx0_o, rs_s0, rs_d0, rp0, ei0, W1r0, b1r0,
                                      att1_fcW, att1_fcb, att1_v, sc + 0, mt0, NT);
  k_rowagg<1><<<gNT, BT, 0, stream>>>(Tx0_t, rs_s2, rs_d2, rp2, ei2, W1r2, b1r2,
                                      att1_fcW, att1_fcb, att1_v, sc + 1, mt2, NT);
  k_rowagg<0><<<gNO, BT, 0, stream>>>(Tx0_t, rs_s1, rs_d1, rp1, ei1, W1r1, b1r1,
                                      nullptr, nullptr, nullptr, nullptr, Tx1_o, NO);

  k_gpr<<<gNT, BT, 0, stream>>>(Tx0_t, projW, projb, gamma, 0, hidden, NT);
  k_combgpr<<<gNT, BT, 0, stream>>>(mt0, mt2, sc, 0, 1, 1.0f / NT, Tx0_t, Tx1_t,
                                    projW, projb, gamma, 1, hidden, NT, 0);

  // ---- loop-invariant m_t0 (layer 2) + att2 score slot 2 ----
  k_rowagg<1><<<gNT, BT, 0, stream>>>(Tx1_o, rs_s0, rs_d0, rp0, ei0, W2r0, b2r0,
                                      att2_fcW, att2_fcb, att2_v, sc + 2, mt0, NT);

  // ---- GPR propagation loop ----
  for (int k = 1; k < KORD; ++k) {
    k_rowagg<1><<<gNT, BT, 0, stream>>>(Tx1_t, rs_s2, rs_d2, rp2, ei2, W2r2, b2r2,
                                        att2_fcW, att2_fcb, att2_v, sc + 2 + k, mt2, NT);
    k_combgpr<<<gNT, BT, 0, stream>>>(mt0, mt2, sc, 2, 2 + k, 1.0f / NT, Tx0_t, Tx2_t,
                                      projW, projb, gamma, k + 1, hidden, NT, 1);
    float* tmp = Tx0_t; Tx0_t = Tx1_t; Tx1_t = Tx2_t; Tx2_t = tmp;
  }

  // ---- finals ----
  dim3 adjGrid((NT + 127) / 128, (NT + 127) / 128);
  k_adj<<<adjGrid, 256, 0, stream>>>(hidden, out + ADJ_OFF, NT);
  k_tanhv<<<(NT * 64 + BT - 1) / BT, BT, 0, stream>>>(hidden, out + H_OFF, NT * 64);
  k_gemmN64<128><<<gNT, BT, 0, stream>>>(z_pre, p3W, p3b, zp, NT);

  k_loss<<<gNT, BT, 0, stream>>>(out + H_OFF, zp, sc + 12, NT);
  k_finalize<<<1, 1, 0, stream>>>(sc + 12, out + LOSS_OFF);

  k_rowgemm<64><<<NT, 128, 0, stream>>>(out + H_OFF, p1W1, p1b1, t1, 128, 1);
  k_rowgemm<128><<<NT, 256, 0, stream>>>(t1, p1W2, p1b2, out + XPRE_OFF, 334, 2);
  k_rowgemm<64><<<NT, 128, 0, stream>>>(zp, p1W1, p1b1, t1, 128, 1);
  k_rowgemm<128><<<NT, 256, 0, stream>>>(t1, p1W2, p1b2, out + ZPRE_OFF, 334, 2);
  k_logits<<<(NT * 3 + BT - 1) / BT, BT, 0, stream>>>(out + H_OFF, outW, outb,
                                                      out + LOGITS_OFF, NT);
}